// Round 3
// baseline (178.430 us; speedup 1.0000x reference)
//
#include <hip/hip_runtime.h>
#include <math.h>

#define HW 262144   // 512*512
#define KTOP 512

// ---------------- ws layout (bytes) ----------------
// region0: hist (8*4096*4 = 131072) then reused as cand (8*4096*8 = 262144)
// cnt:    8 * 128       = 1024     @ 262144   (128B stride: no shared-line atomics)
// thr:    8 * 4         = 32       @ 263168
// rowAny: 8 * 8 * 8     = 512      @ 263200
// sup:    8 * 512 * 8*8 = 262144   @ 263712
// boxes:  8 * 512 * 8*4 = 131072   @ 525856   (end 656928)
#define OFF_HIST 0
#define OFF_CAND 0
#define OFF_CNT  262144
#define OFF_THR  263168
#define OFF_ANY  263200
#define OFF_SUP  263712
#define OFF_BOX  525856
#define ZERO_BYTES 525856

__device__ __forceinline__ unsigned sortkey(float f) {
  unsigned u = __float_as_uint(f);
  return (u & 0x80000000u) ? ~u : (u | 0x80000000u);
}

// Bit-replica of XLA-CPU f32 logistic: 1/(1+exp(-x)) via correctly-rounded exp.
// Verified exact in R1/R2 (absmax 0.0). Do not touch.
__device__ __forceinline__ float xla_sigmoid(float x) {
  float e = (float)exp(-(double)x);
  float d = __fadd_rn(1.0f, e);
  return __fdiv_rn(1.0f, d);
}

// ---------------- phase 1: logit histogram (top 12 bits of sortable key) ----
__global__ void __launch_bounds__(256) k_hist(const float* __restrict__ in,
                                              unsigned* __restrict__ hist) {
  __shared__ unsigned sh[4096];
  int b = blockIdx.x >> 8, sl = blockIdx.x & 255;
  for (int i = threadIdx.x; i < 4096; i += 256) sh[i] = 0u;
  __syncthreads();
  const float* p = in + (size_t)b * 9 * HW;   // channel 0 = conf logit plane
  int base = sl * 1024 + threadIdx.x * 4;
  float4 v = *(const float4*)(p + base);
  atomicAdd(&sh[sortkey(v.x) >> 20], 1u);
  atomicAdd(&sh[sortkey(v.y) >> 20], 1u);
  atomicAdd(&sh[sortkey(v.z) >> 20], 1u);
  atomicAdd(&sh[sortkey(v.w) >> 20], 1u);
  __syncthreads();
  for (int i = threadIdx.x; i < 4096; i += 256) {
    unsigned c = sh[i];
    if (c) atomicAdd(&hist[b * 4096 + i], c);
  }
}

// ---------------- phase 2: find threshold bin (suffix count >= 512) ---------
__global__ void __launch_bounds__(64) k_thresh(const unsigned* __restrict__ hist,
                                               unsigned* __restrict__ thr) {
  int b = blockIdx.x, lane = threadIdx.x;
  const unsigned* h = hist + b * 4096;
  int hi = 4095 - 64 * lane;
  unsigned s = 0;
  for (int k = 0; k < 64; k++) s += h[hi - k];
  unsigned cum = s;
  for (int d = 1; d < 64; d <<= 1) {
    unsigned t = __shfl_up(cum, d, 64);
    if (lane >= d) cum += t;
  }
  unsigned long long m = __ballot(cum >= 512u);
  int first = __ffsll(m) - 1;
  if (lane == first) {
    unsigned run = cum - s;
    int bstar = hi - 63;
    for (int k = 0; k < 64; k++) {
      run += h[hi - k];
      if (run >= 512u) { bstar = hi - k; break; }
    }
    thr[b] = (unsigned)bstar;
  }
}

// ---------------- phase 3: compact candidates (block-aggregated atomic) -----
__global__ void __launch_bounds__(256) k_compact(const float* __restrict__ in,
                                                 const unsigned* __restrict__ thr,
                                                 unsigned* __restrict__ cnt,
                                                 unsigned long long* __restrict__ cand) {
  __shared__ unsigned scnt, sbase;
  int b = blockIdx.x >> 8, sl = blockIdx.x & 255;
  if (threadIdx.x == 0) scnt = 0u;
  unsigned T = thr[b];
  const float* p = in + (size_t)b * 9 * HW;
  int base = sl * 1024 + threadIdx.x * 4;
  float4 v = *(const float4*)(p + base);
  float vv0 = v.x, vv1 = v.y, vv2 = v.z, vv3 = v.w;
  __syncthreads();
  bool c0 = (sortkey(vv0) >> 20) >= T;
  bool c1 = (sortkey(vv1) >> 20) >= T;
  bool c2 = (sortkey(vv2) >> 20) >= T;
  bool c3 = (sortkey(vv3) >> 20) >= T;
  int lc = (int)c0 + (int)c1 + (int)c2 + (int)c3;
  unsigned mypos = 0;
  if (lc) mypos = atomicAdd(&scnt, (unsigned)lc);
  __syncthreads();
  if (threadIdx.x == 0 && scnt) sbase = atomicAdd(&cnt[b * 32], scnt);
  __syncthreads();
  if (lc) {
    unsigned mybase = sbase + mypos;
    unsigned long long* dst = cand + (size_t)b * 4096;
    int o1 = c0, o2 = o1 + c1, o3 = o2 + c2;
    if (c0 && mybase < 4096u) {
      dst[mybase] = ((unsigned long long)__float_as_uint(xla_sigmoid(vv0)) << 32) | (unsigned)(~(unsigned)(base + 0));
    }
    if (c1 && mybase + o1 < 4096u) {
      dst[mybase + o1] = ((unsigned long long)__float_as_uint(xla_sigmoid(vv1)) << 32) | (unsigned)(~(unsigned)(base + 1));
    }
    if (c2 && mybase + o2 < 4096u) {
      dst[mybase + o2] = ((unsigned long long)__float_as_uint(xla_sigmoid(vv2)) << 32) | (unsigned)(~(unsigned)(base + 2));
    }
    if (c3 && mybase + o3 < 4096u) {
      dst[mybase + o3] = ((unsigned long long)__float_as_uint(xla_sigmoid(vv3)) << 32) | (unsigned)(~(unsigned)(base + 3));
    }
  }
}

// ---------------- phase 4: sort candidates, decode top-512 ------------------
__global__ void __launch_bounds__(1024) k_sortdecode(const float* __restrict__ in,
                                                     const unsigned* __restrict__ cnt,
                                                     const unsigned long long* __restrict__ cand,
                                                     float* __restrict__ boxes) {
  __shared__ unsigned long long s[4096];
  int b = blockIdx.x;
  unsigned n = cnt[b * 32]; if (n > 4096u) n = 4096u;
  // smallest power-of-two sort size >= n (n >= 512 by threshold construction)
  int S = (n <= 1024u) ? 1024 : ((n <= 2048u) ? 2048 : 4096);
  for (int i = threadIdx.x; i < S; i += 1024)
    s[i] = (i < (int)n) ? cand[(size_t)b * 4096 + i] : 0ull;
  __syncthreads();
  for (int k = 2; k <= S; k <<= 1) {
    for (int j = k >> 1; j > 0; j >>= 1) {
      for (int e = 0; e < S; e += 1024) {
        int i = threadIdx.x + e;
        int ixj = i ^ j;
        if (ixj > i) {
          bool dirDesc = ((i & k) == 0);
          unsigned long long a = s[i], c = s[ixj];
          if ((a < c) == dirDesc) { s[i] = c; s[ixj] = a; }
        }
      }
      __syncthreads();
    }
  }
  int t = threadIdx.x;
  if (t < KTOP) {
    unsigned long long key = s[t];
    float* dst = boxes + ((size_t)b * KTOP + t) * 8;
    if ((unsigned)(key >> 32) == 0u) {   // impossible in practice; safety
      #pragma unroll
      for (int c = 0; c < 8; c++) dst[c] = 0.0f;
    } else {
      unsigned pix = ~(unsigned)(key & 0xffffffffull);
      float conf = __uint_as_float((unsigned)(key >> 32));
      const float* p = in + (size_t)b * 9 * HW;
      float o1 = p[1 * HW + pix], o2 = p[2 * HW + pix], o3 = p[3 * HW + pix];
      float o4 = p[4 * HW + pix], o5 = p[5 * HW + pix], o6 = p[6 * HW + pix];
      float o7 = p[7 * HW + pix], o8 = p[8 * HW + pix];
      float x = xla_sigmoid(o1) + (float)(pix & 511);
      float y = xla_sigmoid(o2) + (float)(pix >> 9);
      float z = xla_sigmoid(o3) * 4.0f;
      float l = expf(o4) * 3.9f;
      float w = expf(o5) * 1.6f;
      float h = expf(o6) * 1.56f;
      float yw = atan2f(tanhf(o7), tanhf(o8));
      dst[0] = conf; dst[1] = x; dst[2] = y; dst[3] = z;
      dst[4] = l; dst[5] = w; dst[6] = h; dst[7] = yw;
    }
  }
}

// ---------------- rotated-box IoU (fp32 mirror of the reference) ------------
#define CE_(I, J) {                                                         \
  bool sw_ = (ang[I] > ang[J]) || ((ang[I] == ang[J]) && (oi[I] > oi[J]));  \
  if (sw_) { float tf_; int ti_;                                            \
    tf_ = ang[I]; ang[I] = ang[J]; ang[J] = tf_;                            \
    ti_ = oi[I];  oi[I]  = oi[J];  oi[J]  = ti_;                            \
    tf_ = qx[I];  qx[I]  = qx[J];  qx[J]  = tf_;                            \
    tf_ = qy[I];  qy[I]  = qy[J];  qy[J]  = tf_; } }

#define MPASS(P, R, D)                                                      \
  _Pragma("unroll")                                                         \
  for (int i_ = 0; i_ < 32 - (D); i_++) {                                   \
    if ((i_ & (P)) == (R)) CE_(i_, i_ + (D));                               \
  }

__device__ float pair_iou3d(const float a[7], const float b[7]) {
  const float KLX[4] = {0.5f, 0.5f, -0.5f, -0.5f};
  const float KLY[4] = {0.5f, -0.5f, -0.5f, 0.5f};
  float cax[4], cay[4], cbx[4], cby[4];
  float cA = cosf(a[6]), sA = sinf(a[6]);
  float cB = cosf(b[6]), sB = sinf(b[6]);
  #pragma unroll
  for (int k = 0; k < 4; k++) {
    float lx = KLX[k] * a[3], ly = KLY[k] * a[4];
    cax[k] = a[0] + lx * cA - ly * sA;
    cay[k] = a[1] + lx * sA + ly * cA;
    lx = KLX[k] * b[3]; ly = KLY[k] * b[4];
    cbx[k] = b[0] + lx * cB - ly * sB;
    cby[k] = b[1] + lx * sB + ly * cB;
  }
  float px[24], py[24]; bool val[24];
  #pragma unroll
  for (int ai = 0; ai < 4; ai++) {
    float a1x = cax[ai], a1y = cay[ai];
    float rx = cax[(ai + 1) & 3] - a1x, ry = cay[(ai + 1) & 3] - a1y;
    #pragma unroll
    for (int bj = 0; bj < 4; bj++) {
      float b1x = cbx[bj], b1y = cby[bj];
      float sx = cbx[(bj + 1) & 3] - b1x, sy = cby[(bj + 1) & 3] - b1y;
      float qpx = b1x - a1x, qpy = b1y - a1y;
      float den = rx * sy - ry * sx;
      bool dok = fabsf(den) > 1e-8f;
      float safe = dok ? den : 1.0f;
      float t = (qpx * sy - qpy * sx) / safe;
      float u = (qpx * ry - qpy * rx) / safe;
      bool ok = dok && (t >= 0.0f) && (t <= 1.0f) && (u >= 0.0f) && (u <= 1.0f);
      px[ai * 4 + bj] = a1x + t * rx;
      py[ai * 4 + bj] = a1y + t * ry;
      val[ai * 4 + bj] = ok;
    }
  }
  #pragma unroll
  for (int k = 0; k < 4; k++) {
    px[16 + k] = cax[k]; py[16 + k] = cay[k];
    { float dx = cax[k] - b[0], dy = cay[k] - b[1];
      float lx = dx * cB + dy * sB, ly = -dx * sB + dy * cB;
      val[16 + k] = (fabsf(lx) <= b[3] * 0.5f + 1e-6f) &&
                    (fabsf(ly) <= b[4] * 0.5f + 1e-6f); }
    px[20 + k] = cbx[k]; py[20 + k] = cby[k];
    { float dx = cbx[k] - a[0], dy = cby[k] - a[1];
      float lx = dx * cA + dy * sA, ly = -dx * sA + dy * cA;
      val[20 + k] = (fabsf(lx) <= a[3] * 0.5f + 1e-6f) &&
                    (fabsf(ly) <= a[4] * 0.5f + 1e-6f); }
  }
  float n = 0.0f, sxs = 0.0f, sys = 0.0f;
  #pragma unroll
  for (int k = 0; k < 24; k++) {
    float vf = val[k] ? 1.0f : 0.0f;
    n += vf; sxs += px[k] * vf; sys += py[k] * vf;
  }
  float inv = fmaxf(n, 1.0f);
  float ctrx = sxs / inv, ctry = sys / inv;
  float fx = px[0], fy = py[0]; bool found = false;
  #pragma unroll
  for (int k = 0; k < 24; k++) {
    bool take = val[k] && !found;
    if (take) { fx = px[k]; fy = py[k]; }
    found = found || val[k];
  }
  float ang[32], qx[32], qy[32]; int oi[32];
  #pragma unroll
  for (int k = 0; k < 24; k++) {
    float X = val[k] ? px[k] : fx, Y = val[k] ? py[k] : fy;
    qx[k] = X; qy[k] = Y; oi[k] = k;
    ang[k] = atan2f(Y - ctry, X - ctrx);
  }
  #pragma unroll
  for (int k = 24; k < 32; k++) {
    qx[k] = 0.0f; qy[k] = 0.0f; oi[k] = k;
    ang[k] = __int_as_float(0x7f800000);
  }
  MPASS(16, 0, 16);
  MPASS(8, 0, 8);  MPASS(8, 8, 8);
  MPASS(4, 0, 4);  MPASS(4, 4, 12); MPASS(4, 4, 4);
  MPASS(2, 0, 2);  MPASS(2, 2, 14); MPASS(2, 2, 6);  MPASS(2, 2, 2);
  MPASS(1, 0, 1);  MPASS(1, 1, 15); MPASS(1, 1, 7);  MPASS(1, 1, 3); MPASS(1, 1, 1);
  float area2 = 0.0f;
  #pragma unroll
  for (int k = 0; k < 24; k++) {
    int k2 = (k + 1) % 24;
    float x1 = qx[k] - ctrx, y1 = qy[k] - ctry;
    float x2 = qx[k2] - ctrx, y2 = qy[k2] - ctry;
    area2 += x1 * y2 - y1 * x2;
  }
  float area = 0.5f * fabsf(area2);
  if (!(n >= 3.0f)) area = 0.0f;
  float z1 = fmaxf(a[2] - a[5] * 0.5f, b[2] - b[5] * 0.5f);
  float z2 = fminf(a[2] + a[5] * 0.5f, b[2] + b[5] * 0.5f);
  float inter = area * fmaxf(z2 - z1, 0.0f);
  float va = a[3] * a[4] * a[5], vb = b[3] * b[4] * b[5];
  return inter / (va + vb - inter + 1e-8f);
}

// ---------------- phase 5: all-pairs sweep, LDS-resident --------------------
// 64 blocks = 8 batches x 8 row-groups (64 rows each). 512 threads; thread j
// owns box j in registers. Survivors of the cheap reject go to an LDS queue
// (flushed every 8 rows => cap 8*512 = 4096, provably no overflow), then
// drained lane-parallel so heavy pair_iou3d calls don't serialize per-wave.
__global__ void __launch_bounds__(512) k_iou(const float* __restrict__ boxes,
                                             unsigned long long* __restrict__ sup,
                                             unsigned long long* __restrict__ rowAny) {
  __shared__ float sb[KTOP * 8];        // 16 KB: batch's boxes
  __shared__ unsigned queue[4096];      // 16 KB: surviving pairs
  __shared__ unsigned qn;
  int b = blockIdx.x >> 3, rowbase = (blockIdx.x & 7) * 64;
  int t = threadIdx.x;
  const float4* src = (const float4*)(boxes + (size_t)b * KTOP * 8);
  ((float4*)sb)[t] = src[t];
  ((float4*)sb)[t + 512] = src[t + 512];
  __syncthreads();
  // own box
  float b7[7];
  #pragma unroll
  for (int c = 0; c < 7; c++) b7[c] = sb[t * 8 + 1 + c];
  float rb = 0.5f * sqrtf(b7[3] * b7[3] + b7[4] * b7[4]);
  float bz1 = b7[2] - b7[5] * 0.5f, bz2 = b7[2] + b7[5] * 0.5f;

  for (int g = 0; g < 8; g++) {
    if (t == 0) qn = 0u;
    __syncthreads();
    #pragma unroll
    for (int r = 0; r < 8; r++) {
      int i = rowbase + g * 8 + r;
      float aconf = sb[i * 8];                      // LDS broadcast
      if (aconf <= 0.5f || t <= i) continue;
      float ax = sb[i * 8 + 1], ay = sb[i * 8 + 2], az = sb[i * 8 + 3];
      float al = sb[i * 8 + 4], aw = sb[i * 8 + 5], ah = sb[i * 8 + 6];
      float dx = b7[0] - ax, dy = b7[1] - ay;
      float ra = 0.5f * sqrtf(al * al + aw * aw);
      float rs = (ra + rb) * 1.001f + 0.01f;        // disjoint circles => IoU 0
      if (dx * dx + dy * dy > rs * rs) continue;
      float z1 = fmaxf(az - ah * 0.5f, bz1);
      float z2 = fminf(az + ah * 0.5f, bz2);
      if (!(z2 - z1 > 0.0f)) continue;              // inter = area*max(dz,0)=0
      unsigned pos = atomicAdd(&qn, 1u);
      queue[pos] = ((unsigned)i << 16) | (unsigned)t;
    }
    __syncthreads();
    unsigned nq = qn;
    for (unsigned q = t; q < nq; q += 512) {
      unsigned e = queue[q];
      int i = (int)(e >> 16), j = (int)(e & 0xffffu);
      float a7[7], c7[7];
      #pragma unroll
      for (int c = 0; c < 7; c++) { a7[c] = sb[i * 8 + 1 + c]; c7[c] = sb[j * 8 + 1 + c]; }
      float iou = pair_iou3d(a7, c7);
      if (iou > 0.1f) {
        atomicOr(&sup[((size_t)b * KTOP + i) * 8 + (j >> 6)], 1ull << (j & 63));
        atomicOr(&rowAny[b * 8 + (i >> 6)], 1ull << (i & 63));
      }
    }
    __syncthreads();
  }
}

// ---------------- phase 6: sequential NMS on bitmasks + output --------------
__global__ void __launch_bounds__(512) k_nms_out(const float* __restrict__ boxes,
                                                 const unsigned long long* __restrict__ sup,
                                                 const unsigned long long* __restrict__ rowAny,
                                                 float* __restrict__ out) {
  int b = blockIdx.x, t = threadIdx.x;
  __shared__ unsigned long long kw[8];
  float conf = boxes[((size_t)b * KTOP + t) * 8];
  unsigned long long m = __ballot(conf > 0.5f);
  if ((t & 63) == 0) kw[t >> 6] = m;
  __syncthreads();
  if (t == 0) {
    unsigned long long kp[8];
    #pragma unroll
    for (int w = 0; w < 8; w++) kp[w] = kw[w];
    unsigned long long anyw[8];
    #pragma unroll
    for (int w = 0; w < 8; w++) anyw[w] = rowAny[b * 8 + w];
    #pragma unroll
    for (int w = 0; w < 8; w++) {
      unsigned long long act = kp[w] & anyw[w];
      while (act) {
        int bit = __ffsll(act) - 1;
        act &= act - 1;
        const unsigned long long* row = sup + ((size_t)b * KTOP + (w * 64 + bit)) * 8;
        #pragma unroll
        for (int u = 0; u < 8; u++) kp[u] &= ~row[u];
        act &= kp[w];
      }
    }
    #pragma unroll
    for (int w = 0; w < 8; w++) kw[w] = kp[w];
  }
  __syncthreads();
  bool kept = (kw[t >> 6] >> (t & 63)) & 1ull;
  const float* src = boxes + ((size_t)b * KTOP + t) * 8;
  float* dst = out + ((size_t)b * KTOP + t) * 8;
  #pragma unroll
  for (int c = 0; c < 8; c++) dst[c] = kept ? src[c] : 0.0f;
}

extern "C" void kernel_launch(void* const* d_in, const int* in_sizes, int n_in,
                              void* d_out, int out_size, void* d_ws, size_t ws_size,
                              hipStream_t stream) {
  const float* in = (const float*)d_in[0];   // (8, 9, 512, 512) f32
  float* out = (float*)d_out;                // (8, 512, 8) f32
  char* ws = (char*)d_ws;
  unsigned* hist = (unsigned*)(ws + OFF_HIST);
  unsigned long long* cand = (unsigned long long*)(ws + OFF_CAND); // aliases hist
  unsigned* cnt = (unsigned*)(ws + OFF_CNT);
  unsigned* thr = (unsigned*)(ws + OFF_THR);
  unsigned long long* rowAny = (unsigned long long*)(ws + OFF_ANY);
  unsigned long long* sup = (unsigned long long*)(ws + OFF_SUP);
  float* boxes = (float*)(ws + OFF_BOX);

  hipMemsetAsync(d_ws, 0, ZERO_BYTES, stream);
  k_hist<<<dim3(2048), dim3(256), 0, stream>>>(in, hist);
  k_thresh<<<dim3(8), dim3(64), 0, stream>>>(hist, thr);
  k_compact<<<dim3(2048), dim3(256), 0, stream>>>(in, thr, cnt, cand);
  k_sortdecode<<<dim3(8), dim3(1024), 0, stream>>>(in, cnt, cand, boxes);
  k_iou<<<dim3(64), dim3(512), 0, stream>>>(boxes, sup, rowAny);
  k_nms_out<<<dim3(8), dim3(512), 0, stream>>>(boxes, sup, rowAny, out);
}

// Round 4
// 86.816 us; speedup vs baseline: 2.0553x; 2.0553x over previous
//
#include <hip/hip_runtime.h>
#include <math.h>

#define HW 262144   // 512*512
#define KTOP 512
#define QCAP 16384

// ---------------- ws layout (bytes) ----------------
// region0: hist (8*4096*4 = 131072) then reused as cand (8*4096*8 = 262144)
// cnt:    8 * 128       = 1024     @ 262144
// thr:    8 * 4         = 32       @ 263168
// rowAny: 8 * 8 * 8     = 512      @ 263200
// sup:    8 * 512 * 8*8 = 262144   @ 263712  (end 525856)
// boxes:  8 * 512 * 8*4 = 131072   @ 525856  (end 656928)
// qcnt:   128                      @ 656928
// queue:  16384 * 4     = 65536    @ 657056  (end 722592)
#define OFF_HIST 0
#define OFF_CAND 0
#define OFF_CNT  262144
#define OFF_THR  263168
#define OFF_ANY  263200
#define OFF_SUP  263712
#define OFF_BOX  525856
#define OFF_QCNT 656928
#define OFF_QUEUE 657056
#define ZERO_BYTES 657056   // through qcnt (boxes zeroing harmless; fully rewritten)

__device__ __forceinline__ unsigned sortkey(float f) {
  unsigned u = __float_as_uint(f);
  return (u & 0x80000000u) ? ~u : (u | 0x80000000u);
}

// Bit-replica of XLA-CPU f32 logistic. Verified exact R1-R3 (absmax 0.0).
__device__ __forceinline__ float xla_sigmoid(float x) {
  float e = (float)exp(-(double)x);
  float d = __fadd_rn(1.0f, e);
  return __fdiv_rn(1.0f, d);
}

// ---------------- phase 1: logit histogram ----------------------------------
__global__ void __launch_bounds__(256) k_hist(const float* __restrict__ in,
                                              unsigned* __restrict__ hist) {
  __shared__ unsigned sh[4096];
  int b = blockIdx.x >> 8, sl = blockIdx.x & 255;
  for (int i = threadIdx.x; i < 4096; i += 256) sh[i] = 0u;
  __syncthreads();
  const float* p = in + (size_t)b * 9 * HW;
  int base = sl * 1024 + threadIdx.x * 4;
  float4 v = *(const float4*)(p + base);
  atomicAdd(&sh[sortkey(v.x) >> 20], 1u);
  atomicAdd(&sh[sortkey(v.y) >> 20], 1u);
  atomicAdd(&sh[sortkey(v.z) >> 20], 1u);
  atomicAdd(&sh[sortkey(v.w) >> 20], 1u);
  __syncthreads();
  for (int i = threadIdx.x; i < 4096; i += 256) {
    unsigned c = sh[i];
    if (c) atomicAdd(&hist[b * 4096 + i], c);
  }
}

// ---------------- phase 2: threshold bin ------------------------------------
__global__ void __launch_bounds__(64) k_thresh(const unsigned* __restrict__ hist,
                                               unsigned* __restrict__ thr) {
  int b = blockIdx.x, lane = threadIdx.x;
  const unsigned* h = hist + b * 4096;
  int hi = 4095 - 64 * lane;
  unsigned s = 0;
  for (int k = 0; k < 64; k++) s += h[hi - k];
  unsigned cum = s;
  for (int d = 1; d < 64; d <<= 1) {
    unsigned t = __shfl_up(cum, d, 64);
    if (lane >= d) cum += t;
  }
  unsigned long long m = __ballot(cum >= 512u);
  int first = __ffsll(m) - 1;
  if (lane == first) {
    unsigned run = cum - s;
    int bstar = hi - 63;
    for (int k = 0; k < 64; k++) {
      run += h[hi - k];
      if (run >= 512u) { bstar = hi - k; break; }
    }
    thr[b] = (unsigned)bstar;
  }
}

// ---------------- phase 3: compact candidates -------------------------------
__global__ void __launch_bounds__(256) k_compact(const float* __restrict__ in,
                                                 const unsigned* __restrict__ thr,
                                                 unsigned* __restrict__ cnt,
                                                 unsigned long long* __restrict__ cand) {
  __shared__ unsigned scnt, sbase;
  int b = blockIdx.x >> 8, sl = blockIdx.x & 255;
  if (threadIdx.x == 0) scnt = 0u;
  unsigned T = thr[b];
  const float* p = in + (size_t)b * 9 * HW;
  int base = sl * 1024 + threadIdx.x * 4;
  float4 v = *(const float4*)(p + base);
  float vv0 = v.x, vv1 = v.y, vv2 = v.z, vv3 = v.w;
  __syncthreads();
  bool c0 = (sortkey(vv0) >> 20) >= T;
  bool c1 = (sortkey(vv1) >> 20) >= T;
  bool c2 = (sortkey(vv2) >> 20) >= T;
  bool c3 = (sortkey(vv3) >> 20) >= T;
  int lc = (int)c0 + (int)c1 + (int)c2 + (int)c3;
  unsigned mypos = 0;
  if (lc) mypos = atomicAdd(&scnt, (unsigned)lc);
  __syncthreads();
  if (threadIdx.x == 0 && scnt) sbase = atomicAdd(&cnt[b * 32], scnt);
  __syncthreads();
  if (lc) {
    unsigned mybase = sbase + mypos;
    unsigned long long* dst = cand + (size_t)b * 4096;
    int o1 = c0, o2 = o1 + c1, o3 = o2 + c2;
    if (c0 && mybase < 4096u)
      dst[mybase] = ((unsigned long long)__float_as_uint(xla_sigmoid(vv0)) << 32) | (unsigned)(~(unsigned)(base + 0));
    if (c1 && mybase + o1 < 4096u)
      dst[mybase + o1] = ((unsigned long long)__float_as_uint(xla_sigmoid(vv1)) << 32) | (unsigned)(~(unsigned)(base + 1));
    if (c2 && mybase + o2 < 4096u)
      dst[mybase + o2] = ((unsigned long long)__float_as_uint(xla_sigmoid(vv2)) << 32) | (unsigned)(~(unsigned)(base + 2));
    if (c3 && mybase + o3 < 4096u)
      dst[mybase + o3] = ((unsigned long long)__float_as_uint(xla_sigmoid(vv3)) << 32) | (unsigned)(~(unsigned)(base + 3));
  }
}

// ---------------- phase 4: sort candidates, decode top-512 ------------------
__global__ void __launch_bounds__(1024) k_sortdecode(const float* __restrict__ in,
                                                     const unsigned* __restrict__ cnt,
                                                     const unsigned long long* __restrict__ cand,
                                                     float* __restrict__ boxes) {
  __shared__ unsigned long long s[4096];
  int b = blockIdx.x;
  unsigned n = cnt[b * 32]; if (n > 4096u) n = 4096u;
  int S = (n <= 1024u) ? 1024 : ((n <= 2048u) ? 2048 : 4096);
  for (int i = threadIdx.x; i < S; i += 1024)
    s[i] = (i < (int)n) ? cand[(size_t)b * 4096 + i] : 0ull;
  __syncthreads();
  for (int k = 2; k <= S; k <<= 1) {
    for (int j = k >> 1; j > 0; j >>= 1) {
      for (int e = 0; e < S; e += 1024) {
        int i = threadIdx.x + e;
        int ixj = i ^ j;
        if (ixj > i) {
          bool dirDesc = ((i & k) == 0);
          unsigned long long a = s[i], c = s[ixj];
          if ((a < c) == dirDesc) { s[i] = c; s[ixj] = a; }
        }
      }
      __syncthreads();
    }
  }
  int t = threadIdx.x;
  if (t < KTOP) {
    unsigned long long key = s[t];
    float* dst = boxes + ((size_t)b * KTOP + t) * 8;
    if ((unsigned)(key >> 32) == 0u) {
      #pragma unroll
      for (int c = 0; c < 8; c++) dst[c] = 0.0f;
    } else {
      unsigned pix = ~(unsigned)(key & 0xffffffffull);
      float conf = __uint_as_float((unsigned)(key >> 32));
      const float* p = in + (size_t)b * 9 * HW;
      float o1 = p[1 * HW + pix], o2 = p[2 * HW + pix], o3 = p[3 * HW + pix];
      float o4 = p[4 * HW + pix], o5 = p[5 * HW + pix], o6 = p[6 * HW + pix];
      float o7 = p[7 * HW + pix], o8 = p[8 * HW + pix];
      float x = xla_sigmoid(o1) + (float)(pix & 511);
      float y = xla_sigmoid(o2) + (float)(pix >> 9);
      float z = xla_sigmoid(o3) * 4.0f;
      float l = expf(o4) * 3.9f;
      float w = expf(o5) * 1.6f;
      float h = expf(o6) * 1.56f;
      float yw = atan2f(tanhf(o7), tanhf(o8));
      dst[0] = conf; dst[1] = x; dst[2] = y; dst[3] = z;
      dst[4] = l; dst[5] = w; dst[6] = h; dst[7] = yw;
    }
  }
}

// ---------------- rotated-box IoU (fp32 mirror of the reference) ------------
#define CE_(I, J) {                                                         \
  bool sw_ = (ang[I] > ang[J]) || ((ang[I] == ang[J]) && (oi[I] > oi[J]));  \
  if (sw_) { float tf_; int ti_;                                            \
    tf_ = ang[I]; ang[I] = ang[J]; ang[J] = tf_;                            \
    ti_ = oi[I];  oi[I]  = oi[J];  oi[J]  = ti_;                            \
    tf_ = qx[I];  qx[I]  = qx[J];  qx[J]  = tf_;                            \
    tf_ = qy[I];  qy[I]  = qy[J];  qy[J]  = tf_; } }

#define MPASS(P, R, D)                                                      \
  _Pragma("unroll")                                                         \
  for (int i_ = 0; i_ < 32 - (D); i_++) {                                   \
    if ((i_ & (P)) == (R)) CE_(i_, i_ + (D));                               \
  }

__device__ float pair_iou3d(const float a[7], const float b[7]) {
  const float KLX[4] = {0.5f, 0.5f, -0.5f, -0.5f};
  const float KLY[4] = {0.5f, -0.5f, -0.5f, 0.5f};
  float cax[4], cay[4], cbx[4], cby[4];
  float cA = cosf(a[6]), sA = sinf(a[6]);
  float cB = cosf(b[6]), sB = sinf(b[6]);
  #pragma unroll
  for (int k = 0; k < 4; k++) {
    float lx = KLX[k] * a[3], ly = KLY[k] * a[4];
    cax[k] = a[0] + lx * cA - ly * sA;
    cay[k] = a[1] + lx * sA + ly * cA;
    lx = KLX[k] * b[3]; ly = KLY[k] * b[4];
    cbx[k] = b[0] + lx * cB - ly * sB;
    cby[k] = b[1] + lx * sB + ly * cB;
  }
  float px[24], py[24]; bool val[24];
  #pragma unroll
  for (int ai = 0; ai < 4; ai++) {
    float a1x = cax[ai], a1y = cay[ai];
    float rx = cax[(ai + 1) & 3] - a1x, ry = cay[(ai + 1) & 3] - a1y;
    #pragma unroll
    for (int bj = 0; bj < 4; bj++) {
      float b1x = cbx[bj], b1y = cby[bj];
      float sx = cbx[(bj + 1) & 3] - b1x, sy = cby[(bj + 1) & 3] - b1y;
      float qpx = b1x - a1x, qpy = b1y - a1y;
      float den = rx * sy - ry * sx;
      bool dok = fabsf(den) > 1e-8f;
      float safe = dok ? den : 1.0f;
      float t = (qpx * sy - qpy * sx) / safe;
      float u = (qpx * ry - qpy * rx) / safe;
      bool ok = dok && (t >= 0.0f) && (t <= 1.0f) && (u >= 0.0f) && (u <= 1.0f);
      px[ai * 4 + bj] = a1x + t * rx;
      py[ai * 4 + bj] = a1y + t * ry;
      val[ai * 4 + bj] = ok;
    }
  }
  #pragma unroll
  for (int k = 0; k < 4; k++) {
    px[16 + k] = cax[k]; py[16 + k] = cay[k];
    { float dx = cax[k] - b[0], dy = cay[k] - b[1];
      float lx = dx * cB + dy * sB, ly = -dx * sB + dy * cB;
      val[16 + k] = (fabsf(lx) <= b[3] * 0.5f + 1e-6f) &&
                    (fabsf(ly) <= b[4] * 0.5f + 1e-6f); }
    px[20 + k] = cbx[k]; py[20 + k] = cby[k];
    { float dx = cbx[k] - a[0], dy = cby[k] - a[1];
      float lx = dx * cA + dy * sA, ly = -dx * sA + dy * cA;
      val[20 + k] = (fabsf(lx) <= a[3] * 0.5f + 1e-6f) &&
                    (fabsf(ly) <= a[4] * 0.5f + 1e-6f); }
  }
  float n = 0.0f, sxs = 0.0f, sys = 0.0f;
  #pragma unroll
  for (int k = 0; k < 24; k++) {
    float vf = val[k] ? 1.0f : 0.0f;
    n += vf; sxs += px[k] * vf; sys += py[k] * vf;
  }
  float inv = fmaxf(n, 1.0f);
  float ctrx = sxs / inv, ctry = sys / inv;
  float fx = px[0], fy = py[0]; bool found = false;
  #pragma unroll
  for (int k = 0; k < 24; k++) {
    bool take = val[k] && !found;
    if (take) { fx = px[k]; fy = py[k]; }
    found = found || val[k];
  }
  float ang[32], qx[32], qy[32]; int oi[32];
  #pragma unroll
  for (int k = 0; k < 24; k++) {
    float X = val[k] ? px[k] : fx, Y = val[k] ? py[k] : fy;
    qx[k] = X; qy[k] = Y; oi[k] = k;
    ang[k] = atan2f(Y - ctry, X - ctrx);
  }
  #pragma unroll
  for (int k = 24; k < 32; k++) {
    qx[k] = 0.0f; qy[k] = 0.0f; oi[k] = k;
    ang[k] = __int_as_float(0x7f800000);
  }
  MPASS(16, 0, 16);
  MPASS(8, 0, 8);  MPASS(8, 8, 8);
  MPASS(4, 0, 4);  MPASS(4, 4, 12); MPASS(4, 4, 4);
  MPASS(2, 0, 2);  MPASS(2, 2, 14); MPASS(2, 2, 6);  MPASS(2, 2, 2);
  MPASS(1, 0, 1);  MPASS(1, 1, 15); MPASS(1, 1, 7);  MPASS(1, 1, 3); MPASS(1, 1, 1);
  float area2 = 0.0f;
  #pragma unroll
  for (int k = 0; k < 24; k++) {
    int k2 = (k + 1) % 24;
    float x1 = qx[k] - ctrx, y1 = qy[k] - ctry;
    float x2 = qx[k2] - ctrx, y2 = qy[k2] - ctry;
    area2 += x1 * y2 - y1 * x2;
  }
  float area = 0.5f * fabsf(area2);
  if (!(n >= 3.0f)) area = 0.0f;
  float z1 = fmaxf(a[2] - a[5] * 0.5f, b[2] - b[5] * 0.5f);
  float z2 = fminf(a[2] + a[5] * 0.5f, b[2] + b[5] * 0.5f);
  float inter = area * fmaxf(z2 - z1, 0.0f);
  float va = a[3] * a[4] * a[5], vb = b[3] * b[4] * b[5];
  return inter / (va + vb - inter + 1e-8f);
}

// ---------------- phase 5a: cheap reject -> global pair queue ---------------
// 64 blocks = 8 batches x 8 row-groups (64 rows). Thread j owns box j (regs);
// row-i fields come from LDS broadcasts (stride-9 padding: conflict-free).
// Survivors accumulate in an LDS queue; one global atomicAdd per block.
__global__ void __launch_bounds__(512) k_pairs(const float* __restrict__ boxes,
                                               unsigned* __restrict__ qcnt,
                                               unsigned* __restrict__ queue) {
  __shared__ float sb[KTOP * 9];        // 18 KB, stride 9
  __shared__ unsigned lq[2048];
  __shared__ unsigned lqn, lbase;
  int b = blockIdx.x >> 3, rowbase = (blockIdx.x & 7) * 64;
  int t = threadIdx.x;
  if (t == 0) lqn = 0u;
  const float4* src = (const float4*)(boxes + (size_t)b * KTOP * 8);
  float4 u0 = src[t * 2], u1 = src[t * 2 + 1];
  sb[t * 9 + 0] = u0.x; sb[t * 9 + 1] = u0.y; sb[t * 9 + 2] = u0.z;
  sb[t * 9 + 3] = u0.w; sb[t * 9 + 4] = u1.x; sb[t * 9 + 5] = u1.y;
  sb[t * 9 + 6] = u1.z; sb[t * 9 + 7] = u1.w;
  __syncthreads();
  // own box (j = t) from registers
  float bx = u0.y, by = u0.z, bz = u0.w, bl = u1.x, bw = u1.y, bh = u1.z;
  float rb = 0.5f * sqrtf(bl * bl + bw * bw);
  float bz1 = bz - bh * 0.5f, bz2 = bz + bh * 0.5f;
  for (int i = rowbase; i < rowbase + 64; i++) {
    if (t <= i) continue;
    float aconf = sb[i * 9];                       // broadcast (free)
    if (aconf <= 0.5f) continue;
    float ax = sb[i * 9 + 1], ay = sb[i * 9 + 2], az = sb[i * 9 + 3];
    float al = sb[i * 9 + 4], aw = sb[i * 9 + 5], ah = sb[i * 9 + 6];
    float dx = bx - ax, dy = by - ay;
    float ra = 0.5f * sqrtf(al * al + aw * aw);
    float rs = (ra + rb) * 1.001f + 0.01f;         // disjoint circles => IoU 0
    if (dx * dx + dy * dy > rs * rs) continue;
    float z1 = fmaxf(az - ah * 0.5f, bz1);
    float z2 = fminf(az + ah * 0.5f, bz2);
    if (!(z2 - z1 > 0.0f)) continue;               // inter = area*max(dz,0)=0
    unsigned pos = atomicAdd(&lqn, 1u);
    if (pos < 2048u) lq[pos] = ((unsigned)b << 18) | ((unsigned)i << 9) | (unsigned)t;
  }
  __syncthreads();
  unsigned n = lqn; if (n > 2048u) n = 2048u;
  if (t == 0 && n) lbase = atomicAdd(qcnt, n);
  __syncthreads();
  if (n) {
    unsigned base = lbase;
    for (unsigned q = t; q < n; q += 512) {
      unsigned g = base + q;
      if (g < QCAP) queue[g] = lq[q];
    }
  }
}

// ---------------- phase 5b: heavy IoU, one pair per lane --------------------
__global__ void __launch_bounds__(256) k_iou_heavy(const float* __restrict__ boxes,
                                                   const unsigned* __restrict__ qcnt,
                                                   const unsigned* __restrict__ queue,
                                                   unsigned long long* __restrict__ sup,
                                                   unsigned long long* __restrict__ rowAny) {
  unsigned total = *qcnt; if (total > QCAP) total = QCAP;
  for (unsigned q = blockIdx.x * 256 + threadIdx.x; q < total;
       q += gridDim.x * 256) {
    unsigned e = queue[q];
    int b = (int)(e >> 18), i = (int)((e >> 9) & 511u), j = (int)(e & 511u);
    const float* A = boxes + ((size_t)b * KTOP + i) * 8;
    const float* Bp = boxes + ((size_t)b * KTOP + j) * 8;
    float a7[7], b7[7];
    #pragma unroll
    for (int c = 0; c < 7; c++) { a7[c] = A[1 + c]; b7[c] = Bp[1 + c]; }
    float iou = pair_iou3d(a7, b7);
    if (iou > 0.1f) {
      atomicOr(&sup[((size_t)b * KTOP + i) * 8 + (j >> 6)], 1ull << (j & 63));
      atomicOr(&rowAny[b * 8 + (i >> 6)], 1ull << (i & 63));
    }
  }
}

// ---------------- phase 6: sequential NMS on bitmasks + output --------------
__global__ void __launch_bounds__(512) k_nms_out(const float* __restrict__ boxes,
                                                 const unsigned long long* __restrict__ sup,
                                                 const unsigned long long* __restrict__ rowAny,
                                                 float* __restrict__ out) {
  int b = blockIdx.x, t = threadIdx.x;
  __shared__ unsigned long long kw[8];
  float conf = boxes[((size_t)b * KTOP + t) * 8];
  unsigned long long m = __ballot(conf > 0.5f);
  if ((t & 63) == 0) kw[t >> 6] = m;
  __syncthreads();
  if (t == 0) {
    unsigned long long kp[8];
    #pragma unroll
    for (int w = 0; w < 8; w++) kp[w] = kw[w];
    unsigned long long anyw[8];
    #pragma unroll
    for (int w = 0; w < 8; w++) anyw[w] = rowAny[b * 8 + w];
    #pragma unroll
    for (int w = 0; w < 8; w++) {
      unsigned long long act = kp[w] & anyw[w];
      while (act) {
        int bit = __ffsll(act) - 1;
        act &= act - 1;
        const unsigned long long* row = sup + ((size_t)b * KTOP + (w * 64 + bit)) * 8;
        #pragma unroll
        for (int u = 0; u < 8; u++) kp[u] &= ~row[u];
        act &= kp[w];
      }
    }
    #pragma unroll
    for (int w = 0; w < 8; w++) kw[w] = kp[w];
  }
  __syncthreads();
  bool kept = (kw[t >> 6] >> (t & 63)) & 1ull;
  const float* src = boxes + ((size_t)b * KTOP + t) * 8;
  float* dst = out + ((size_t)b * KTOP + t) * 8;
  #pragma unroll
  for (int c = 0; c < 8; c++) dst[c] = kept ? src[c] : 0.0f;
}

extern "C" void kernel_launch(void* const* d_in, const int* in_sizes, int n_in,
                              void* d_out, int out_size, void* d_ws, size_t ws_size,
                              hipStream_t stream) {
  const float* in = (const float*)d_in[0];   // (8, 9, 512, 512) f32
  float* out = (float*)d_out;                // (8, 512, 8) f32
  char* ws = (char*)d_ws;
  unsigned* hist = (unsigned*)(ws + OFF_HIST);
  unsigned long long* cand = (unsigned long long*)(ws + OFF_CAND); // aliases hist
  unsigned* cnt = (unsigned*)(ws + OFF_CNT);
  unsigned* thr = (unsigned*)(ws + OFF_THR);
  unsigned long long* rowAny = (unsigned long long*)(ws + OFF_ANY);
  unsigned long long* sup = (unsigned long long*)(ws + OFF_SUP);
  float* boxes = (float*)(ws + OFF_BOX);
  unsigned* qcnt = (unsigned*)(ws + OFF_QCNT);
  unsigned* queue = (unsigned*)(ws + OFF_QUEUE);

  hipMemsetAsync(d_ws, 0, ZERO_BYTES, stream);
  k_hist<<<dim3(2048), dim3(256), 0, stream>>>(in, hist);
  k_thresh<<<dim3(8), dim3(64), 0, stream>>>(hist, thr);
  k_compact<<<dim3(2048), dim3(256), 0, stream>>>(in, thr, cnt, cand);
  k_sortdecode<<<dim3(8), dim3(1024), 0, stream>>>(in, cnt, cand, boxes);
  k_pairs<<<dim3(64), dim3(512), 0, stream>>>(boxes, qcnt, queue);
  k_iou_heavy<<<dim3(64), dim3(256), 0, stream>>>(boxes, qcnt, queue, sup, rowAny);
  k_nms_out<<<dim3(8), dim3(512), 0, stream>>>(boxes, sup, rowAny, out);
}